// Round 7
// baseline (19335.767 us; speedup 1.0000x reference)
//
#include <hip/hip_runtime.h>

#define T_STEPS 1000
#define BATCH   256
#define NIN     128
#define NHID    512
#define NOUT    128
#define ROWS    16
#define NBLK    16

typedef _Float16 half8   __attribute__((ext_vector_type(8)));
typedef float    floatx4 __attribute__((ext_vector_type(4)));

__device__ __forceinline__ half8 f8_to_h8(const float* __restrict__ p) {
  floatx4 lo = *(const floatx4*)p;
  floatx4 hi = *(const floatx4*)(p + 4);
  half8 r;
#pragma unroll
  for (int i = 0; i < 4; ++i) { r[i] = (_Float16)lo[i]; r[i + 4] = (_Float16)hi[i]; }
  return r;
}

// ---------------------------------------------------------------------------
// Workspace: 512 KiB of fp16 weight fragments in MFMA-B order, streamed from
// L2 every step by ALL blocks (shared read-only copy -> L2-resident per XCD).
// Per wave w (0..3), frag f (0..127), 1 KiB each (64 lanes x 16 B):
//   f in [0,64):   Wrec  kk = 8+(f>>3), tt = f&7   (K-chunks 8..15, cols w*128+tt*16+..)
//   f in [64,96):  Win   kk = (f-64)>>3, tt = (f-64)&7
//   f in [96,128): Wout  kk = (f-96)>>1, tt = (f-96)&1  (out cols w*32+tt*16+..)
// B-frag (mfma_f32_16x16x32_f16): lane l holds W[col0+(l&15)][kk*32+(l>>4)*8+j]
// ---------------------------------------------------------------------------
__global__ void prep_weights_kernel(const float* __restrict__ Win,
                                    const float* __restrict__ Wrec,
                                    const float* __restrict__ Wout,
                                    _Float16* __restrict__ wsf) {
  const int fid = blockIdx.x;      // 0..511 = w*128 + f
  const int l   = threadIdx.x;     // 0..63
  const int w = fid >> 7, f = fid & 127;
  const int lr = l & 15, lq = l >> 4;
  const float* src; int col, K, kk, tt;
  if (f < 64)      { kk = 8 + (f >> 3);  tt = f & 7;
                     src = Wrec; K = NHID; col = w*128 + tt*16 + lr; }
  else if (f < 96) { int g = f - 64; kk = g >> 3; tt = g & 7;
                     src = Win;  K = NIN;  col = w*128 + tt*16 + lr; }
  else             { int g = f - 96; kk = g >> 1; tt = g & 1;
                     src = Wout; K = NHID; col = w*32  + tt*16 + lr; }
  half8 v = f8_to_h8(src + (size_t)col * K + kk*32 + lq*8);
  ((half8*)wsf)[(size_t)fid * 64 + l] = v;
}

// ---------------------------------------------------------------------------
// 16 blocks x 256 thr (4 waves), one block per 16 batch rows, FULL hidden dim
// on-CU: zero inter-block communication. s_t lives in LDS between steps.
// LDS map: [0,131072)       Wrec kk 4..7 B-frags: (w*32+(kk-4)*8+tt)*1024+l*16
//          [131072,147456)  s stage: 16 A-frags x 1 KiB (frag kk = hidden cols
//                           [kk*32,+32); lane l = row l&15, k=(l>>4)*8+j)
// ---------------------------------------------------------------------------
#define STAGE 131072

__global__ __launch_bounds__(256, 1) void bnn_local_kernel(
    const float* __restrict__ X,     // [T,B,NIN]
    const float* __restrict__ Wrec,  // [NHID,NHID] f32
    const float* __restrict__ bin,   // [NHID]
    const float* __restrict__ bout,  // [NOUT]
    float* __restrict__ out,         // [T,B,NOUT]
    const _Float16* __restrict__ wsf)
{
  __shared__ __attribute__((aligned(16))) char smem[147456];
  const int tid = threadIdx.x;
  const int l   = tid & 63;
  const int w   = tid >> 6;          // wave 0..3: hidden cols [w*128,+128), out cols [w*32,+32)
  const int lr  = l & 15;
  const int lq  = l >> 4;
  const int m0  = blockIdx.x * ROWS;
  const int cw  = w * 128;

  // ---- zero s stage (s_{-1} = 0): 256 thr x 64 B ----
#pragma unroll
  for (int i = 0; i < 4; ++i)
    *(int4*)(smem + STAGE + tid * 64 + i * 16) = make_int4(0, 0, 0, 0);

  // ---- VGPR-resident Wrec K-chunks 0..3 (8 tiles x 4 = 128 VGPR) ----
  half8 wr[8][4];
#pragma unroll
  for (int tt = 0; tt < 8; ++tt)
#pragma unroll
    for (int kk = 0; kk < 4; ++kk)
      wr[tt][kk] = f8_to_h8(Wrec + (size_t)(cw + tt*16 + lr) * NHID + kk*32 + lq*8);

  // ---- LDS-resident Wrec K-chunks 4..7 (32 KiB/wave, own frags only) ----
#pragma unroll
  for (int kk = 0; kk < 4; ++kk)
#pragma unroll
    for (int tt = 0; tt < 8; ++tt) {
      half8 v = f8_to_h8(Wrec + (size_t)(cw + tt*16 + lr) * NHID + (kk + 4)*32 + lq*8);
      *(half8*)(smem + (size_t)(w*32 + kk*8 + tt) * 1024 + l * 16) = v;
    }

  float binv[8];
#pragma unroll
  for (int tt = 0; tt < 8; ++tt) binv[tt] = bin[cw + tt*16 + lr];
  float bo[2];
#pragma unroll
  for (int tt = 0; tt < 2; ++tt) bo[tt] = bout[w*32 + tt*16 + lr];

  const half8* wst = (const half8*)wsf + (size_t)w * 128 * 64;  // wave's stream frags

  // ---- GLIFR state: 8 tiles x 4 rows per lane (32 elems per array) ----
  float v[32], a0[32], a1[32], sp[32];
#pragma unroll
  for (int i = 0; i < 32; ++i) { v[i] = 0.f; a0[i] = 0.f; a1[i] = 0.f; sp[i] = 0.f; }

  const float C_VI = (float)(0.05 * 0.2 * (0.1 + 1.0 / 512.0));  // DT*K_M*R_HID

  __syncthreads();   // stage zero + Wrec LDS visible

#pragma unroll 1
  for (int t = 0; t <= T_STEPS; ++t) {
    // ---- X_t loads first: HBM latency hides under the K-loop ----
    floatx4 xlo[4], xhi[4];
    if (t < T_STEPS) {
      const float* xt = X + ((size_t)t * BATCH + m0 + lr) * NIN + lq * 8;
#pragma unroll
      for (int kk = 0; kk < 4; ++kk) {
        xlo[kk] = *(const floatx4*)(xt + kk * 32);
        xhi[kk] = *(const floatx4*)(xt + kk * 32 + 4);
      }
    }

    floatx4 acc[8], oacc[2];
#pragma unroll
    for (int tt = 0; tt < 8; ++tt)
      acc[tt][0] = acc[tt][1] = acc[tt][2] = acc[tt][3] = binv[tt];
#pragma unroll
    for (int tt = 0; tt < 2; ++tt)
      oacc[tt][0] = oacc[tt][1] = oacc[tt][2] = oacc[tt][3] = bo[tt];

    // ---- K-loop: recurrence (s_{t-1}@Wrec.T) + readout (s_{t-1}@Wout.T).
    //      A-frags from LDS stage; B from VGPR / LDS / L2 stream. ----
#pragma unroll
    for (int kk = 0; kk < 16; ++kk) {
      half8 sf = *(const half8*)(smem + STAGE + kk * 1024 + l * 16);
#pragma unroll
      for (int tt = 0; tt < 2; ++tt) {
        half8 wof = wst[(size_t)(96 + kk*2 + tt) * 64 + l];          // Wout stream
        oacc[tt] = __builtin_amdgcn_mfma_f32_16x16x32_f16(sf, wof, oacc[tt], 0, 0, 0);
      }
#pragma unroll
      for (int tt = 0; tt < 8; ++tt) {
        half8 wb;
        if (kk < 4)      wb = wr[tt][kk];                            // VGPR
        else if (kk < 8) wb = *(const half8*)(smem + (size_t)(w*32 + (kk-4)*8 + tt) * 1024 + l * 16);
        else             wb = wst[(size_t)((kk-8)*8 + tt) * 64 + l]; // L2 stream
        acc[tt] = __builtin_amdgcn_mfma_f32_16x16x32_f16(sf, wb, acc[tt], 0, 0, 0);
      }
    }

    // ---- input projection x_t @ Win.T (streamed Win frags) ----
    if (t < T_STEPS) {
#pragma unroll
      for (int kk = 0; kk < 4; ++kk) {
        half8 xa;
#pragma unroll
        for (int i = 0; i < 4; ++i) {
          xa[i]     = (_Float16)xlo[kk][i];
          xa[i + 4] = (_Float16)xhi[kk][i];
        }
#pragma unroll
        for (int tt = 0; tt < 8; ++tt) {
          half8 wif = wst[(size_t)(64 + kk*8 + tt) * 64 + l];
          acc[tt] = __builtin_amdgcn_mfma_f32_16x16x32_f16(xa, wif, acc[tt], 0, 0, 0);
        }
      }
    }

    // ---- store out[t-1] = s_{t-1} @ Wout.T + bout (fire-and-forget) ----
    if (t >= 1) {
      float* op = out + ((size_t)(t - 1) * BATCH + m0 + lq * 4) * NOUT + w * 32 + lr;
#pragma unroll
      for (int tt = 0; tt < 2; ++tt)
#pragma unroll
        for (int r = 0; r < 4; ++r)
          op[(size_t)r * NOUT + tt * 16] = oacc[tt][r];
    }

    __syncthreads();   // all waves done reading stage s_{t-1}

    // ---- GLIFR pointwise update -> scatter s_t into the stage ----
    if (t < T_STEPS) {
#pragma unroll
      for (int tt = 0; tt < 8; ++tt)
#pragma unroll
        for (int r = 0; r < 4; ++r) {
          const int i = tt*4 + r;
          const float y  = 0.5f * acc[tt][r];                 // avg of the 2 inputs
          a0[i] = a0[i] * 0.85f - 0.05f * sp[i];              // 1-DT*3,  -DT
          a1[i] = a1[i] * -0.5f - 0.05f * sp[i];              // 1-DT*30, -DT
          const float it = y + a0[i] + a1[i] + 700.0f;        // + I0
          v[i] = v[i] * 0.99f * (1.0f - 0.05f * sp[i]) + C_VI * it;
          const float s = 20.0f / (1.0f + __expf(-0.02f * v[i]));  // 20*sigmoid(v/50)
          sp[i] = s;
          const int colw = tt*16 + lr;                        // col within wave slice
          const int kks  = w*4 + (colw >> 5);                 // dest stage frag
          const int koff = colw & 31;
          const int dl   = (lq*4 + r) + 16*(koff >> 3);       // dest lane
          *(_Float16*)(smem + STAGE + kks*1024 + dl*16 + (koff & 7)*2) = (_Float16)s;
        }
    }

    __syncthreads();   // s_t visible to all waves for next step
  }
}

extern "C" void kernel_launch(void* const* d_in, const int* in_sizes, int n_in,
                              void* d_out, int out_size, void* d_ws, size_t ws_size,
                              hipStream_t stream) {
  const float* X    = (const float*)d_in[0];
  const float* Win  = (const float*)d_in[1];
  const float* bin  = (const float*)d_in[2];
  const float* Wrec = (const float*)d_in[3];
  const float* Wout = (const float*)d_in[4];
  const float* bout = (const float*)d_in[5];
  float* out = (float*)d_out;
  _Float16* wsf = (_Float16*)d_ws;   // 512 KiB stream region

  hipLaunchKernelGGL(prep_weights_kernel, dim3(512), dim3(64), 0, stream,
                     Win, Wrec, Wout, wsf);
  hipLaunchKernelGGL(bnn_local_kernel, dim3(NBLK), dim3(256), 0, stream,
                     X, Wrec, bin, bout, out, wsf);
}